// Round 11
// baseline (201.076 us; speedup 1.0000x reference)
//
#include <hip/hip_runtime.h>

// LSTM: B=2048, T=512, INPUT=2, H=32, OUT=1.
// Round 15 = Round 14 (lane-packed 2 elem/wave + f16 h-history + fdot2,
// session best 146.2us) with the i/f/o gate dots moved to v_pk_fma_f16:
//  - R14 counters: busy 480cy/pair-step, of which 256 = 64 fdot2 @ ~4cy
//    (fdot2 issues at packed-fp32 rate, NOT f16 rate). CDNA packed-f16
//    VALU is 2x the packed-f32 rate -> pk_fma_f16 chains @ 2cy halve the
//    MAC issue for the 3 sigmoid gates.
//  - g-gate (tanh, slope 1 at 0: error-sensitive) stays on fdot2 f32-accum.
//  - i/f/o: 2 chains of depth 8 in f16, pk_add_f16 merge, f32 horizontal
//    reduce onto the fp32 x-proj seed. Pre-act error ~2-4e-3 max; through
//    sigmoid slope <=1/4 -> <1e-3 on h. Harness absmax floor is the bf16
//    reference granularity (2^-9) with threshold 9.3e-3: ample headroom.
// If neutral (pk_fma_f16 also 4cy) -> revert R14, declare issue floor.
// Structure carried verbatim from R14/R11: lanes 0..31 elem A, 32..63 elem
// B; lane owns rows i_j,f_j,g_j,o_j of unit j=lane&31 (all lane-local, no
// exchange); f16 h history rows double as broadcast source (4x b128, 2-way
// uniform addr = free); log2e folded into weights; c in 2*log2e scale;
// h = fma(2*o, sigm(c'), -o); bare v_exp_f32; x prefetched 4 steps ahead;
// per-chunk FC flush (lane j handles timestep j, fdot2).

#define BB 2048
#define TT 512
#define HH 32
#define CHUNK 32
#define ROWH 40                         // f16 per history row (80 B, 16B-aligned)
#define WSH (2 * CHUNK * ROWH + 8)      // per-wave LDS f16 count

#define LOG2E 1.44269504088896340736f

typedef float v2f __attribute__((ext_vector_type(2)));
typedef float v4f __attribute__((ext_vector_type(4)));
typedef unsigned int v4u __attribute__((ext_vector_type(4)));
typedef _Float16 h2 __attribute__((ext_vector_type(2)));

__device__ __forceinline__ float sigm2(float xs) {
    // xs is log2e-scaled: returns 1/(1+2^-xs) = sigmoid(xs/log2e)
    return __builtin_amdgcn_rcpf(1.0f + __builtin_amdgcn_exp2f(-xs));
}

__device__ __forceinline__ h2 u2h(unsigned int u) {
    return __builtin_bit_cast(h2, u);
}

#if defined(__has_builtin)
#if __has_builtin(__builtin_amdgcn_fdot2)
#define FDOT2(a, b, c) __builtin_amdgcn_fdot2((a), (b), (c), false)
#endif
#endif
#ifndef FDOT2
#define FDOT2(a, b, c) fmaf((float)(a).y, (float)(b).y, \
                            fmaf((float)(a).x, (float)(b).x, (c)))
#endif

__global__ __launch_bounds__(256, 1) void lstm_fused_kernel(
    const float* __restrict__ x,     // [B, T, 2]
    const float* __restrict__ W_ih,  // [128, 2]
    const float* __restrict__ W_hh,  // [128, 32]
    const float* __restrict__ b_ih,  // [128]
    const float* __restrict__ b_hh,  // [128]
    const float* __restrict__ W_fc,  // [1, 32]
    const float* __restrict__ b_fc,  // [1]
    float* __restrict__ out)         // [B, T, 1]
{
    __shared__ __align__(16) _Float16 lds_h[4][WSH];   // ~20.5 KB history A|B

    const int lane = threadIdx.x & 63;
    const int wv   = threadIdx.x >> 6;
    const int j    = lane & 31;
    const bool low = (lane < 32);
    const int b    = blockIdx.x * 8 + wv * 2 + (low ? 0 : 1);

    // gate rows for unit j (PyTorch order: i, f, g, o)
    const int ri = j, rf = HH + j, rg = 2 * HH + j, ro = 3 * HH + j;
    const float si = LOG2E;              // i, f, o scale
    const float sg = 2.0f * LOG2E;       // g scale (tanh doubling folded in)

    // x-projection weights/biases stay fp32
    const v2f wihI = ((const v2f*)W_ih)[ri] * si;
    const v2f wihF = ((const v2f*)W_ih)[rf] * si;
    const v2f wihG = ((const v2f*)W_ih)[rg] * sg;
    const v2f wihO = ((const v2f*)W_ih)[ro] * si;
    const float bI = (b_ih[ri] + b_hh[ri]) * si;
    const float bF = (b_ih[rf] + b_hh[rf]) * si;
    const float bG = (b_ih[rg] + b_hh[rg]) * sg;
    const float bO = (b_ih[ro] + b_hh[ro]) * si;

    // recurrent weights: scaled fp32 -> packed f16 pairs
    h2 wI[16], wF[16], wG[16], wO[16];
    #pragma unroll
    for (int k = 0; k < 16; ++k) {
        v2f a;
        a = ((const v2f*)(W_hh + ri * HH))[k] * si;
        wI[k] = (h2){(_Float16)a.x, (_Float16)a.y};
        a = ((const v2f*)(W_hh + rf * HH))[k] * si;
        wF[k] = (h2){(_Float16)a.x, (_Float16)a.y};
        a = ((const v2f*)(W_hh + rg * HH))[k] * sg;
        wG[k] = (h2){(_Float16)a.x, (_Float16)a.y};
        a = ((const v2f*)(W_hh + ro * HH))[k] * si;
        wO[k] = (h2){(_Float16)a.x, (_Float16)a.y};
    }

    // FC weights packed f16
    h2 wfc2[16];
    #pragma unroll
    for (int k = 0; k < 16; ++k) {
        v2f a = ((const v2f*)W_fc)[k];
        wfc2[k] = (h2){(_Float16)a.x, (_Float16)a.y};
    }
    const float bfc = b_fc[0];

    float c = 0.0f;   // c' = 2*log2e * c_true

    _Float16* hb = &lds_h[wv][low ? 0 : CHUNK * ROWH];
    _Float16* wr = hb + j;                        // row 0, col j

    hb[(CHUNK - 1) * ROWH + j] = (_Float16)0.0f;  // h_{-1} row = 0

    // h broadcast registers: 32 f16 = 4 x b128 (uniform addr per half-wave)
    v4u hq[4];
    {
        const v4u* rq = (const v4u*)(hb + (CHUNK - 1) * ROWH);
        #pragma unroll
        for (int q = 0; q < 4; ++q) hq[q] = rq[q];
    }

    const float* xb = x + (size_t)b * (TT * 2);
    float* outp = out + (size_t)b * TT + j;

    // x prefetch: 4 timesteps = 2 x b128 (2 unique addrs/wave)
    v4f xq0 = *(const v4f*)(xb);
    v4f xq1 = *(const v4f*)(xb + 4);

    #pragma unroll 1
    for (int ch = 0; ch < TT / CHUNK; ++ch) {
        #pragma unroll 1
        for (int uu = 0; uu < CHUNK; uu += 4) {
            const int t = ch * CHUNK + uu;
            const float* xnx = (t + 4 < TT) ? (xb + (t + 4) * 2) : xb;
            v4f nxq0 = *(const v4f*)(xnx);
            v4f nxq1 = *(const v4f*)(xnx + 4);

            #pragma unroll
            for (int s = 0; s < 4; ++s) {
                v2f xt;
                if      (s == 0) xt = (v2f){xq0.x, xq0.y};
                else if (s == 1) xt = (v2f){xq0.z, xq0.w};
                else if (s == 2) xt = (v2f){xq1.x, xq1.y};
                else             xt = (v2f){xq1.z, xq1.w};

                // x-projection + bias in fp32 (seeds the f32 reduce)
                float aI0 = fmaf(xt.y, wihI.y, fmaf(xt.x, wihI.x, bI));
                float aF0 = fmaf(xt.y, wihF.y, fmaf(xt.x, wihF.x, bF));
                float aG0 = fmaf(xt.y, wihG.y, fmaf(xt.x, wihG.x, bG));
                float aO0 = fmaf(xt.y, wihO.y, fmaf(xt.x, wihO.x, bO));

                // i/f/o recurrent dots: packed f16 FMA, 2 chains of 8 each
                h2 cI0, cI1, cF0, cF1, cO0, cO1;
                // g-gate: f32-accum fdot2 (2 chains of 8)
                float aG1;
                #pragma unroll
                for (int k = 0; k < 16; ++k) {
                    h2 hp = u2h(hq[k >> 2][k & 3]);
                    if (k == 0) {
                        cI0 = hp * wI[k];
                        cF0 = hp * wF[k];
                        cO0 = hp * wO[k];
                        aG0 = FDOT2(hp, wG[k], aG0);
                    } else if (k < 8) {
                        cI0 = __builtin_elementwise_fma(hp, wI[k], cI0);
                        cF0 = __builtin_elementwise_fma(hp, wF[k], cF0);
                        cO0 = __builtin_elementwise_fma(hp, wO[k], cO0);
                        aG0 = FDOT2(hp, wG[k], aG0);
                    } else if (k == 8) {
                        cI1 = hp * wI[k];
                        cF1 = hp * wF[k];
                        cO1 = hp * wO[k];
                        aG1 = FDOT2(hp, wG[k], 0.0f);
                    } else {
                        cI1 = __builtin_elementwise_fma(hp, wI[k], cI1);
                        cF1 = __builtin_elementwise_fma(hp, wF[k], cF1);
                        cO1 = __builtin_elementwise_fma(hp, wO[k], cO1);
                        aG1 = FDOT2(hp, wG[k], aG1);
                    }
                }
                h2 sI = cI0 + cI1;          // v_pk_add_f16
                h2 sF = cF0 + cF1;
                h2 sO = cO0 + cO1;
                float gi = aI0 + ((float)sI.x + (float)sI.y);
                float gf = aF0 + ((float)sF.x + (float)sF.y);
                float go = aO0 + ((float)sO.x + (float)sO.y);
                float gg = aG0 + aG1;

                // activations: all lane-local (fp32)
                float iv = sigm2(gi);
                float fv = sigm2(gf);
                float ov = sigm2(go);
                float gv = fmaf(4.0f * LOG2E, sigm2(gg), -2.0f * LOG2E);

                // c' = f*c' + i*g'   (2*log2e scale)
                c = fmaf(fv, c, iv * gv);

                // h = o*tanh(c) = fma(2*o, sigm(c'), -o)
                float rr   = sigm2(c);
                float hnew = fmaf(ov + ov, rr, -ov);

                // write h_t (f16); that row IS next step's broadcast source
                *wr = (_Float16)hnew;
                {
                    const v4u* rq = (const v4u*)(wr - j);
                    #pragma unroll
                    for (int q = 0; q < 4; ++q) hq[q] = rq[q];
                }
                wr += ROWH;
            }
            xq0 = nxq0; xq1 = nxq1;
        }

        // rewind write ptr; hq carries h across the chunk boundary
        wr -= CHUNK * ROWH;

        // ---- FC flush: lane j handles timestep t'=j of its element ----
        {
            const v4u* fr = (const v4u*)(hb + j * ROWH);
            v4u f[4];
            #pragma unroll
            for (int q = 0; q < 4; ++q) f[q] = fr[q];
            float acc = bfc;
            #pragma unroll
            for (int k = 0; k < 16; ++k)
                acc = FDOT2(u2h(f[k >> 2][k & 3]), wfc2[k], acc);
            *outp = acc;           // out[b][ch*CHUNK + j]
            outp += CHUNK;
        }
    }
}

extern "C" void kernel_launch(void* const* d_in, const int* in_sizes, int n_in,
                              void* d_out, int out_size, void* d_ws, size_t ws_size,
                              hipStream_t stream) {
    const float* x    = (const float*)d_in[0];
    const float* W_ih = (const float*)d_in[1];
    const float* W_hh = (const float*)d_in[2];
    const float* b_ih = (const float*)d_in[3];
    const float* b_hh = (const float*)d_in[4];
    const float* W_fc = (const float*)d_in[5];
    const float* b_fc = (const float*)d_in[6];
    float* out = (float*)d_out;

    dim3 grid(BB / 8);    // 256 blocks x 4 waves x 2 elements = 2048
    dim3 block(256);
    lstm_fused_kernel<<<grid, block, 0, stream>>>(x, W_ih, W_hh, b_ih, b_hh,
                                                  W_fc, b_fc, out);
}

// Round 12
// 199.787 us; speedup vs baseline: 1.0065x; 1.0065x over previous
//
#include <hip/hip_runtime.h>

// LSTM: B=2048, T=512, INPUT=2, H=32, OUT=1.
// Round 16 = Round 14 (lane-packed 2 elem/wave + f16 fdot2 dots, best 146.2us;
// R15's pk_fma_f16 regressed and is reverted) with the LDS h-broadcast
// replaced by a pure-VALU register butterfly:
//  - lane remap: elem = bit4 of lane (16-lane rows A,B,A,B), unit
//    j = (lane&15)|((lane>>1)&16). Same-element lanes = row pairs {0,2}/{1,3}.
//  - per step: permlane32_swap pairs own h with the cross-row h (rows 0<->2,
//    1<->3 = SAME element), pack to f16x2, then 4 levels of mov_dpp
//    row_ror:{1,2,4,8} double the payload within each 16-row -> 16 regs
//    holding all 32 h as f16 pairs. ~20 VALU ops, ~16-20cy chain, vs the
//    ds_write->4x ds_read_b128 round trip (~110cy) it replaces.
//  - SELF-CALIBRATING weight order: at init the identical exchange runs on
//    payload=j; each lane reads back which unit landed in each slot and
//    gathers its (log2e-scaled, f16-packed) W_hh entries in that order from
//    LDS-staged W_hh. Immune to DPP/permlane direction conventions.
//  - h history written f32 to LDS (off-chain now; only read at FC flush,
//    which is f32 again -> slightly more precise than R14's f16 FC).
// Carried from R14: fdot2 f32-accum dots (2 chains of 8 per gate), fp32
// x-proj/bias/acts/c, log2e pre-scaled weights, c in 2*log2e scale,
// h = fma(2*o, sigm(c'), -o), bare v_exp_f32, x prefetched 4 steps ahead,
// per-chunk FC flush (lane j handles timestep j of its element).

#define BB 2048
#define TT 512
#define HH 32
#define CHUNK 32
#define ROWF 33                        // f32 per history row: conflict-free

#define LOG2E 1.44269504088896340736f

typedef float v2f __attribute__((ext_vector_type(2)));
typedef float v4f __attribute__((ext_vector_type(4)));
typedef unsigned int v2u __attribute__((ext_vector_type(2)));
typedef _Float16 h2 __attribute__((ext_vector_type(2)));

__device__ __forceinline__ float sigm2(float xs) {
    // xs is log2e-scaled: returns 1/(1+2^-xs) = sigmoid(xs/log2e)
    return __builtin_amdgcn_rcpf(1.0f + __builtin_amdgcn_exp2f(-xs));
}

__device__ __forceinline__ h2 u2h(unsigned int u) {
    return __builtin_bit_cast(h2, u);
}

#if defined(__has_builtin)
#if __has_builtin(__builtin_amdgcn_fdot2)
#define FDOT2(a, b, c) __builtin_amdgcn_fdot2((a), (b), (c), false)
#endif
#endif
#ifndef FDOT2
#define FDOT2(a, b, c) fmaf((float)(a).y, (float)(b).y, \
                            fmaf((float)(a).x, (float)(b).x, (c)))
#endif

// DPP row rotate-right by amt within each 16-lane row (VALU, ~2cy)
#define DPP_ROR(src, amt) \
    ((unsigned)__builtin_amdgcn_mov_dpp((int)(src), 0x120 | (amt), 0xf, 0xf, true))

__global__ __launch_bounds__(256, 1) void lstm_fused_kernel(
    const float* __restrict__ x,     // [B, T, 2]
    const float* __restrict__ W_ih,  // [128, 2]
    const float* __restrict__ W_hh,  // [128, 32]
    const float* __restrict__ b_ih,  // [128]
    const float* __restrict__ b_hh,  // [128]
    const float* __restrict__ W_fc,  // [1, 32]
    const float* __restrict__ b_fc,  // [1]
    float* __restrict__ out)         // [B, T, 1]
{
    __shared__ float lds_w[128 * HH];                        // 16 KB staged W_hh
    __shared__ __align__(16) float lds_h[4][2 * CHUNK * ROWF]; // 33 KB history

    const int lane = threadIdx.x & 63;
    const int wv   = threadIdx.x >> 6;
    const bool lo32 = (lane < 32);
    const int elem = (lane >> 4) & 1;                 // rows A,B,A,B
    const int j    = (lane & 15) | ((lane >> 1) & 16); // unit index 0..31
    const int b    = blockIdx.x * 8 + wv * 2 + elem;

    // ---- stage W_hh to LDS (vectorized, one barrier) ----
    {
        const v4f* src = (const v4f*)W_hh;
        v4f* dst = (v4f*)lds_w;
        #pragma unroll
        for (int r = 0; r < (128 * HH / 4) / 256; ++r)
            dst[r * 256 + threadIdx.x] = src[r * 256 + threadIdx.x];
    }
    __syncthreads();

    // ---- the exchange network (used for probe AND inner loop) ----
    unsigned P[16];
    auto exch = [&](float hn) {
        // cross-row partner (row0<->row2, row1<->row3 = same element).
        // permlane32_swap pair order per R6 empirics:
        //   .y = cross for lanes<32, .x = cross for lanes>=32
        v2u r = __builtin_amdgcn_permlane32_swap(
            __float_as_uint(hn), __float_as_uint(hn), false, false);
        float hx = __uint_as_float(lo32 ? r.y : r.x);
        h2 pk = {(_Float16)hn, (_Float16)hx};
        P[0] = __builtin_bit_cast(unsigned, pk);
        P[1] = DPP_ROR(P[0], 1);
        P[2] = DPP_ROR(P[0], 2);
        P[3] = DPP_ROR(P[1], 2);
        P[4] = DPP_ROR(P[0], 4);
        P[5] = DPP_ROR(P[1], 4);
        P[6] = DPP_ROR(P[2], 4);
        P[7] = DPP_ROR(P[3], 4);
        P[8]  = DPP_ROR(P[0], 8);
        P[9]  = DPP_ROR(P[1], 8);
        P[10] = DPP_ROR(P[2], 8);
        P[11] = DPP_ROR(P[3], 8);
        P[12] = DPP_ROR(P[4], 8);
        P[13] = DPP_ROR(P[5], 8);
        P[14] = DPP_ROR(P[6], 8);
        P[15] = DPP_ROR(P[7], 8);
    };

    // ---- probe: which unit lands in each slot? (f16 exact for 0..31) ----
    exch((float)j);
    int klo[16], khi[16];
    #pragma unroll
    for (int m = 0; m < 16; ++m) {
        h2 hp = u2h(P[m]);
        klo[m] = (int)(float)hp.x;
        khi[m] = (int)(float)hp.y;
    }

    // gate rows for unit j (PyTorch order: i, f, g, o)
    const int ri = j, rf = HH + j, rg = 2 * HH + j, ro = 3 * HH + j;
    const float si = LOG2E;              // i, f, o scale
    const float sg = 2.0f * LOG2E;       // g scale (tanh doubling folded in)

    // recurrent weights gathered in BUTTERFLY slot order, scaled, f16-packed
    h2 wIp[16], wFp[16], wGp[16], wOp[16];
    #pragma unroll
    for (int m = 0; m < 16; ++m) {
        wIp[m] = (h2){(_Float16)(lds_w[ri * HH + klo[m]] * si),
                      (_Float16)(lds_w[ri * HH + khi[m]] * si)};
        wFp[m] = (h2){(_Float16)(lds_w[rf * HH + klo[m]] * si),
                      (_Float16)(lds_w[rf * HH + khi[m]] * si)};
        wGp[m] = (h2){(_Float16)(lds_w[rg * HH + klo[m]] * sg),
                      (_Float16)(lds_w[rg * HH + khi[m]] * sg)};
        wOp[m] = (h2){(_Float16)(lds_w[ro * HH + klo[m]] * si),
                      (_Float16)(lds_w[ro * HH + khi[m]] * si)};
    }

    // x-projection weights/biases fp32
    const v2f wihI = ((const v2f*)W_ih)[ri] * si;
    const v2f wihF = ((const v2f*)W_ih)[rf] * si;
    const v2f wihG = ((const v2f*)W_ih)[rg] * sg;
    const v2f wihO = ((const v2f*)W_ih)[ro] * si;
    const float bI = (b_ih[ri] + b_hh[ri]) * si;
    const float bF = (b_ih[rf] + b_hh[rf]) * si;
    const float bG = (b_ih[rg] + b_hh[rg]) * sg;
    const float bO = (b_ih[ro] + b_hh[ro]) * si;

    // FC weights (wave-uniform)
    float wfc[HH];
    #pragma unroll
    for (int u = 0; u < HH; ++u) wfc[u] = W_fc[u];
    const float bfc = b_fc[0];

    float c = 0.0f;   // c' = 2*log2e * c_true

    float* hbE = &lds_h[wv][elem * CHUNK * ROWF];
    float* wr  = hbE + j;                 // row 0, col j

    #pragma unroll
    for (int m = 0; m < 16; ++m) P[m] = 0u;   // h_{-1} = 0

    const float* xb = x + (size_t)b * (TT * 2);
    float* outp = out + (size_t)b * TT + j;

    // x prefetch: 4 timesteps = 2 x b128 (2 unique addrs/wave)
    v4f xq0 = *(const v4f*)(xb);
    v4f xq1 = *(const v4f*)(xb + 4);

    #pragma unroll 1
    for (int ch = 0; ch < TT / CHUNK; ++ch) {
        #pragma unroll 1
        for (int uu = 0; uu < CHUNK; uu += 4) {
            const int t = ch * CHUNK + uu;
            const float* xnx = (t + 4 < TT) ? (xb + (t + 4) * 2) : xb;
            v4f nxq0 = *(const v4f*)(xnx);
            v4f nxq1 = *(const v4f*)(xnx + 4);

            #pragma unroll
            for (int s = 0; s < 4; ++s) {
                v2f xt;
                if      (s == 0) xt = (v2f){xq0.x, xq0.y};
                else if (s == 1) xt = (v2f){xq0.z, xq0.w};
                else if (s == 2) xt = (v2f){xq1.x, xq1.y};
                else             xt = (v2f){xq1.z, xq1.w};

                // x-projection + bias in fp32 (seeds chain 0 of each gate)
                float aI0 = fmaf(xt.y, wihI.y, fmaf(xt.x, wihI.x, bI));
                float aF0 = fmaf(xt.y, wihF.y, fmaf(xt.x, wihF.x, bF));
                float aG0 = fmaf(xt.y, wihG.y, fmaf(xt.x, wihG.x, bG));
                float aO0 = fmaf(xt.y, wihO.y, fmaf(xt.x, wihO.x, bO));
                float aI1, aF1, aG1, aO1;

                // recurrent dot: 4 gates x 16 fdot2 (f16 MACs, fp32 accum),
                // h from butterfly regs, weights in matching slot order
                #pragma unroll
                for (int k = 0; k < 16; ++k) {
                    h2 hp = u2h(P[k]);
                    if (k < 8) {
                        aI0 = FDOT2(hp, wIp[k], aI0);
                        aF0 = FDOT2(hp, wFp[k], aF0);
                        aG0 = FDOT2(hp, wGp[k], aG0);
                        aO0 = FDOT2(hp, wOp[k], aO0);
                    } else if (k == 8) {
                        aI1 = FDOT2(hp, wIp[k], 0.0f);
                        aF1 = FDOT2(hp, wFp[k], 0.0f);
                        aG1 = FDOT2(hp, wGp[k], 0.0f);
                        aO1 = FDOT2(hp, wOp[k], 0.0f);
                    } else {
                        aI1 = FDOT2(hp, wIp[k], aI1);
                        aF1 = FDOT2(hp, wFp[k], aF1);
                        aG1 = FDOT2(hp, wGp[k], aG1);
                        aO1 = FDOT2(hp, wOp[k], aO1);
                    }
                }
                float gi = aI0 + aI1;
                float gf = aF0 + aF1;
                float gg = aG0 + aG1;
                float go = aO0 + aO1;

                // activations: all lane-local (fp32)
                float iv = sigm2(gi);
                float fv = sigm2(gf);
                float ov = sigm2(go);
                float gv = fmaf(4.0f * LOG2E, sigm2(gg), -2.0f * LOG2E);

                // c' = f*c' + i*g'   (2*log2e scale)
                c = fmaf(fv, c, iv * gv);

                // h = o*tanh(c) = fma(2*o, sigm(c'), -o)
                float rr   = sigm2(c);
                float hnew = fmaf(ov + ov, rr, -ov);

                // FC history write (f32, off the recurrence chain)
                *wr = hnew;
                wr += ROWF;

                // next step's h: pure-VALU butterfly (no LDS round trip)
                exch(hnew);
            }
            xq0 = nxq0; xq1 = nxq1;
        }

        // rewind write ptr; P regs carry h across the chunk boundary
        wr -= CHUNK * ROWF;

        // ---- FC flush: lane j handles timestep t'=j of its element ----
        {
            const float* frow = hbE + j * ROWF;
            float acc = bfc;
            #pragma unroll
            for (int u = 0; u < HH; ++u)
                acc = fmaf(frow[u], wfc[u], acc);
            *outp = acc;           // out[b][ch*CHUNK + j]
            outp += CHUNK;
        }
    }
}

extern "C" void kernel_launch(void* const* d_in, const int* in_sizes, int n_in,
                              void* d_out, int out_size, void* d_ws, size_t ws_size,
                              hipStream_t stream) {
    const float* x    = (const float*)d_in[0];
    const float* W_ih = (const float*)d_in[1];
    const float* W_hh = (const float*)d_in[2];
    const float* b_ih = (const float*)d_in[3];
    const float* b_hh = (const float*)d_in[4];
    const float* W_fc = (const float*)d_in[5];
    const float* b_fc = (const float*)d_in[6];
    float* out = (float*)d_out;

    dim3 grid(BB / 8);    // 256 blocks x 4 waves x 2 elements = 2048
    dim3 block(256);
    lstm_fused_kernel<<<grid, block, 0, stream>>>(x, W_ih, W_hh, b_ih, b_hh,
                                                  W_fc, b_fc, out);
}

// Round 14
// 190.821 us; speedup vs baseline: 1.0537x; 1.0470x over previous
//
#include <hip/hip_runtime.h>

// LSTM: B=2048, T=512, INPUT=2, H=32, OUT=1.
// Round 18 = Round 17 RESUBMIT (R13 bench failed on container acquisition,
// kernel never ran). R17 = Round 14 revert (session best, 146.2us) + trims.
// R16 post-mortem: DPP/permlane butterfly all-gather was correct (self-
// calibrated) but +72cy/step issue > the ~45cy stall it recovered; third
// confirmation that the LDS h-broadcast (1 write + 4 b128 reads, 2-way
// uniform addr = free) is the cheapest all-gather on this HW.
// Trims vs R14: (1) timestep loop unrolled 8 (was 4): halves loop/prefetch
// overhead, wider scheduler window; (2) chain merges via packed v2f adds;
// (3) x prefetch 4x b128 per 8 steps.
// Structure (R14/R11): lanes 0..31 elem A, 32..63 elem B; lane owns rows
// i_j,f_j,g_j,o_j of unit j=lane&31 (all lane-local, no exchange); f16 h
// history rows double as broadcast source; fdot2 f32-accum dots (2 chains
// of 8 per gate); fp32 x-proj/bias/acts/c; log2e folded into weights; c in
// 2*log2e scale; h = fma(2*o, sigm(c'), -o); bare v_exp_f32; per-chunk FC
// flush (lane j handles timestep j of its element).
// Issue budget (measured): 480cy/pair-step of which 256 = 64 fdot2 (VALU MAC
// floor; MFMA offload analyzed: grid-collapse at E>=16, C-fragment
// redistribution cost at E=2 -> no win). Stall 205cy = LDS RT + act chains.

#define BB 2048
#define TT 512
#define HH 32
#define CHUNK 32
#define ROWH 40                         // f16 per history row (80 B, 16B-aligned)
#define WSH (2 * CHUNK * ROWH + 8)      // per-wave LDS f16 count

#define LOG2E 1.44269504088896340736f

typedef float v2f __attribute__((ext_vector_type(2)));
typedef float v4f __attribute__((ext_vector_type(4)));
typedef unsigned int v4u __attribute__((ext_vector_type(4)));
typedef _Float16 h2 __attribute__((ext_vector_type(2)));

__device__ __forceinline__ float sigm2(float xs) {
    // xs is log2e-scaled: returns 1/(1+2^-xs) = sigmoid(xs/log2e)
    return __builtin_amdgcn_rcpf(1.0f + __builtin_amdgcn_exp2f(-xs));
}

__device__ __forceinline__ h2 u2h(unsigned int u) {
    return __builtin_bit_cast(h2, u);
}

#if defined(__has_builtin)
#if __has_builtin(__builtin_amdgcn_fdot2)
#define FDOT2(a, b, c) __builtin_amdgcn_fdot2((a), (b), (c), false)
#endif
#endif
#ifndef FDOT2
#define FDOT2(a, b, c) fmaf((float)(a).y, (float)(b).y, \
                            fmaf((float)(a).x, (float)(b).x, (c)))
#endif

__global__ __launch_bounds__(256, 1) void lstm_fused_kernel(
    const float* __restrict__ x,     // [B, T, 2]
    const float* __restrict__ W_ih,  // [128, 2]
    const float* __restrict__ W_hh,  // [128, 32]
    const float* __restrict__ b_ih,  // [128]
    const float* __restrict__ b_hh,  // [128]
    const float* __restrict__ W_fc,  // [1, 32]
    const float* __restrict__ b_fc,  // [1]
    float* __restrict__ out)         // [B, T, 1]
{
    __shared__ __align__(16) _Float16 lds_h[4][WSH];   // ~20.5 KB history A|B

    const int lane = threadIdx.x & 63;
    const int wv   = threadIdx.x >> 6;
    const int j    = lane & 31;
    const bool low = (lane < 32);
    const int b    = blockIdx.x * 8 + wv * 2 + (low ? 0 : 1);

    // gate rows for unit j (PyTorch order: i, f, g, o)
    const int ri = j, rf = HH + j, rg = 2 * HH + j, ro = 3 * HH + j;
    const float si = LOG2E;              // i, f, o scale
    const float sg = 2.0f * LOG2E;       // g scale (tanh doubling folded in)

    // x-projection weights/biases stay fp32
    const v2f wihI = ((const v2f*)W_ih)[ri] * si;
    const v2f wihF = ((const v2f*)W_ih)[rf] * si;
    const v2f wihG = ((const v2f*)W_ih)[rg] * sg;
    const v2f wihO = ((const v2f*)W_ih)[ro] * si;
    const float bI = (b_ih[ri] + b_hh[ri]) * si;
    const float bF = (b_ih[rf] + b_hh[rf]) * si;
    const float bG = (b_ih[rg] + b_hh[rg]) * sg;
    const float bO = (b_ih[ro] + b_hh[ro]) * si;

    // recurrent weights: scaled fp32 -> packed f16 pairs
    h2 wI[16], wF[16], wG[16], wO[16];
    #pragma unroll
    for (int k = 0; k < 16; ++k) {
        v2f a;
        a = ((const v2f*)(W_hh + ri * HH))[k] * si;
        wI[k] = (h2){(_Float16)a.x, (_Float16)a.y};
        a = ((const v2f*)(W_hh + rf * HH))[k] * si;
        wF[k] = (h2){(_Float16)a.x, (_Float16)a.y};
        a = ((const v2f*)(W_hh + rg * HH))[k] * sg;
        wG[k] = (h2){(_Float16)a.x, (_Float16)a.y};
        a = ((const v2f*)(W_hh + ro * HH))[k] * si;
        wO[k] = (h2){(_Float16)a.x, (_Float16)a.y};
    }

    // FC weights packed f16
    h2 wfc2[16];
    #pragma unroll
    for (int k = 0; k < 16; ++k) {
        v2f a = ((const v2f*)W_fc)[k];
        wfc2[k] = (h2){(_Float16)a.x, (_Float16)a.y};
    }
    const float bfc = b_fc[0];

    float c = 0.0f;   // c' = 2*log2e * c_true

    _Float16* hb = &lds_h[wv][low ? 0 : CHUNK * ROWH];
    _Float16* wr = hb + j;                        // row 0, col j

    hb[(CHUNK - 1) * ROWH + j] = (_Float16)0.0f;  // h_{-1} row = 0

    // h broadcast registers: 32 f16 = 4 x b128 (uniform addr per half-wave)
    v4u hq[4];
    {
        const v4u* rq = (const v4u*)(hb + (CHUNK - 1) * ROWH);
        #pragma unroll
        for (int q = 0; q < 4; ++q) hq[q] = rq[q];
    }

    const float* xb = x + (size_t)b * (TT * 2);
    float* outp = out + (size_t)b * TT + j;

    // x prefetch: 8 timesteps = 4 x b128 (4 unique addrs/wave)
    v4f xq0 = *(const v4f*)(xb);
    v4f xq1 = *(const v4f*)(xb + 4);
    v4f xq2 = *(const v4f*)(xb + 8);
    v4f xq3 = *(const v4f*)(xb + 12);

    #pragma unroll 1
    for (int ch = 0; ch < TT / CHUNK; ++ch) {
        #pragma unroll 1
        for (int uu = 0; uu < CHUNK; uu += 8) {
            const int t = ch * CHUNK + uu;
            const float* xnx = (t + 8 < TT) ? (xb + (t + 8) * 2) : xb;
            v4f nxq0 = *(const v4f*)(xnx);
            v4f nxq1 = *(const v4f*)(xnx + 4);
            v4f nxq2 = *(const v4f*)(xnx + 8);
            v4f nxq3 = *(const v4f*)(xnx + 12);

            #pragma unroll
            for (int s = 0; s < 8; ++s) {
                v2f xt;
                if      (s == 0) xt = (v2f){xq0.x, xq0.y};
                else if (s == 1) xt = (v2f){xq0.z, xq0.w};
                else if (s == 2) xt = (v2f){xq1.x, xq1.y};
                else if (s == 3) xt = (v2f){xq1.z, xq1.w};
                else if (s == 4) xt = (v2f){xq2.x, xq2.y};
                else if (s == 5) xt = (v2f){xq2.z, xq2.w};
                else if (s == 6) xt = (v2f){xq3.x, xq3.y};
                else             xt = (v2f){xq3.z, xq3.w};

                // x-projection + bias in fp32 (seeds chain 0 of each gate)
                float aI0 = fmaf(xt.y, wihI.y, fmaf(xt.x, wihI.x, bI));
                float aF0 = fmaf(xt.y, wihF.y, fmaf(xt.x, wihF.x, bF));
                float aG0 = fmaf(xt.y, wihG.y, fmaf(xt.x, wihG.x, bG));
                float aO0 = fmaf(xt.y, wihO.y, fmaf(xt.x, wihO.x, bO));
                float aI1, aF1, aG1, aO1;

                // recurrent dot: 4 gates x 16 fdot2 (f16 MACs, fp32 accum),
                // split into 2 chains of 8 per gate
                #pragma unroll
                for (int k = 0; k < 16; ++k) {
                    h2 hp = u2h(hq[k >> 2][k & 3]);
                    if (k < 8) {
                        aI0 = FDOT2(hp, wI[k], aI0);
                        aF0 = FDOT2(hp, wF[k], aF0);
                        aG0 = FDOT2(hp, wG[k], aG0);
                        aO0 = FDOT2(hp, wO[k], aO0);
                    } else if (k == 8) {
                        aI1 = FDOT2(hp, wI[k], 0.0f);
                        aF1 = FDOT2(hp, wF[k], 0.0f);
                        aG1 = FDOT2(hp, wG[k], 0.0f);
                        aO1 = FDOT2(hp, wO[k], 0.0f);
                    } else {
                        aI1 = FDOT2(hp, wI[k], aI1);
                        aF1 = FDOT2(hp, wF[k], aF1);
                        aG1 = FDOT2(hp, wG[k], aG1);
                        aO1 = FDOT2(hp, wO[k], aO1);
                    }
                }
                // chain merges as packed adds (2x v_pk_add_f32)
                v2f gIF = (v2f){aI0, aF0} + (v2f){aI1, aF1};
                v2f gGO = (v2f){aG0, aO0} + (v2f){aG1, aO1};
                float gi = gIF.x, gf = gIF.y;
                float gg = gGO.x, go = gGO.y;

                // activations: all lane-local (fp32)
                float iv = sigm2(gi);
                float fv = sigm2(gf);
                float ov = sigm2(go);
                float gv = fmaf(4.0f * LOG2E, sigm2(gg), -2.0f * LOG2E);

                // c' = f*c' + i*g'   (2*log2e scale)
                c = fmaf(fv, c, iv * gv);

                // h = o*tanh(c) = fma(2*o, sigm(c'), -o)
                float rr   = sigm2(c);
                float hnew = fmaf(ov + ov, rr, -ov);

                // write h_t (f16); that row IS next step's broadcast source
                *wr = (_Float16)hnew;
                {
                    const v4u* rq = (const v4u*)(wr - j);
                    #pragma unroll
                    for (int q = 0; q < 4; ++q) hq[q] = rq[q];
                }
                wr += ROWH;
            }
            xq0 = nxq0; xq1 = nxq1; xq2 = nxq2; xq3 = nxq3;
        }

        // rewind write ptr; hq carries h across the chunk boundary
        wr -= CHUNK * ROWH;

        // ---- FC flush: lane j handles timestep t'=j of its element ----
        {
            const v4u* fr = (const v4u*)(hb + j * ROWH);
            v4u f[4];
            #pragma unroll
            for (int q = 0; q < 4; ++q) f[q] = fr[q];
            float acc = bfc;
            #pragma unroll
            for (int k = 0; k < 16; ++k)
                acc = FDOT2(u2h(f[k >> 2][k & 3]), wfc2[k], acc);
            *outp = acc;           // out[b][ch*CHUNK + j]
            outp += CHUNK;
        }
    }
}

extern "C" void kernel_launch(void* const* d_in, const int* in_sizes, int n_in,
                              void* d_out, int out_size, void* d_ws, size_t ws_size,
                              hipStream_t stream) {
    const float* x    = (const float*)d_in[0];
    const float* W_ih = (const float*)d_in[1];
    const float* W_hh = (const float*)d_in[2];
    const float* b_ih = (const float*)d_in[3];
    const float* b_hh = (const float*)d_in[4];
    const float* W_fc = (const float*)d_in[5];
    const float* b_fc = (const float*)d_in[6];
    float* out = (float*)d_out;

    dim3 grid(BB / 8);    // 256 blocks x 4 waves x 2 elements = 2048
    dim3 block(256);
    lstm_fused_kernel<<<grid, block, 0, stream>>>(x, W_ih, W_hh, b_ih, b_hh,
                                                  W_fc, b_fc, out);
}

// Round 15
// 190.032 us; speedup vs baseline: 1.0581x; 1.0042x over previous
//
#include <hip/hip_runtime.h>

// LSTM: B=2048, T=512, INPUT=2, H=32, OUT=1.
// Round 19 = Round 18 (best, 140.0us rocprof) + packed x-projection:
//  - the 8 scalar v_fma_f32 xproj seeds become 4 v_pk_fma_f32 with
//    loop-invariant packed weight/bias pairs (I,F) and (G,O). Splats
//    encode via VOP3P op_sel; per-half IEEE fma -> bit-identical math.
//    Saves ~16cy of the measured 466cy/pair-step issue (~2.4%).
// Issue budget at R18 (measured): 466cy/pair-step = 256 (64 fdot2, the
// f16-VALU MAC floor, E-invariant) + ~80 (10 trans) + ~130 (misc);
// stall 190cy = LDS RT + act chains at the problem-capped 1 wave/SIMD
// (1024 waves on 1024 SIMDs; E=1@2waves and E=4@0.5waves both worse).
// Six structural stall-attacks all measured worse (readlane +70% busy,
// DPP butterfly +72cy issue, 2-wave split, stagger, zip, pk_f16).
// Structure (R14/R11): lanes 0..31 elem A, 32..63 elem B; lane owns rows
// i_j,f_j,g_j,o_j of unit j=lane&31 (all lane-local, no exchange); f16 h
// history rows double as broadcast source (1 ds_write_b16 + 4 ds_read_b128,
// 2-way uniform addr = free); fdot2 f32-accum dots (2 chains of 8 per
// gate); fp32 bias/acts/c; log2e folded into weights; c in 2*log2e scale;
// h = fma(2*o, sigm(c'), -o); bare v_exp_f32; timestep loop unrolled 8;
// x prefetch 4x b128 per 8 steps; per-chunk FC flush (lane j, timestep j).

#define BB 2048
#define TT 512
#define HH 32
#define CHUNK 32
#define ROWH 40                         // f16 per history row (80 B, 16B-aligned)
#define WSH (2 * CHUNK * ROWH + 8)      // per-wave LDS f16 count

#define LOG2E 1.44269504088896340736f

typedef float v2f __attribute__((ext_vector_type(2)));
typedef float v4f __attribute__((ext_vector_type(4)));
typedef unsigned int v4u __attribute__((ext_vector_type(4)));
typedef _Float16 h2 __attribute__((ext_vector_type(2)));

__device__ __forceinline__ float sigm2(float xs) {
    // xs is log2e-scaled: returns 1/(1+2^-xs) = sigmoid(xs/log2e)
    return __builtin_amdgcn_rcpf(1.0f + __builtin_amdgcn_exp2f(-xs));
}

__device__ __forceinline__ h2 u2h(unsigned int u) {
    return __builtin_bit_cast(h2, u);
}

#if defined(__has_builtin)
#if __has_builtin(__builtin_amdgcn_fdot2)
#define FDOT2(a, b, c) __builtin_amdgcn_fdot2((a), (b), (c), false)
#endif
#endif
#ifndef FDOT2
#define FDOT2(a, b, c) fmaf((float)(a).y, (float)(b).y, \
                            fmaf((float)(a).x, (float)(b).x, (c)))
#endif

__global__ __launch_bounds__(256, 1) void lstm_fused_kernel(
    const float* __restrict__ x,     // [B, T, 2]
    const float* __restrict__ W_ih,  // [128, 2]
    const float* __restrict__ W_hh,  // [128, 32]
    const float* __restrict__ b_ih,  // [128]
    const float* __restrict__ b_hh,  // [128]
    const float* __restrict__ W_fc,  // [1, 32]
    const float* __restrict__ b_fc,  // [1]
    float* __restrict__ out)         // [B, T, 1]
{
    __shared__ __align__(16) _Float16 lds_h[4][WSH];   // ~20.5 KB history A|B

    const int lane = threadIdx.x & 63;
    const int wv   = threadIdx.x >> 6;
    const int j    = lane & 31;
    const bool low = (lane < 32);
    const int b    = blockIdx.x * 8 + wv * 2 + (low ? 0 : 1);

    // gate rows for unit j (PyTorch order: i, f, g, o)
    const int ri = j, rf = HH + j, rg = 2 * HH + j, ro = 3 * HH + j;
    const float si = LOG2E;              // i, f, o scale
    const float sg = 2.0f * LOG2E;       // g scale (tanh doubling folded in)

    // x-projection weights/biases fp32, packed by gate pair (I,F) / (G,O)
    const v2f wihI = ((const v2f*)W_ih)[ri] * si;
    const v2f wihF = ((const v2f*)W_ih)[rf] * si;
    const v2f wihG = ((const v2f*)W_ih)[rg] * sg;
    const v2f wihO = ((const v2f*)W_ih)[ro] * si;
    const v2f wIFx = {wihI.x, wihF.x}, wIFy = {wihI.y, wihF.y};
    const v2f wGOx = {wihG.x, wihO.x}, wGOy = {wihG.y, wihO.y};
    const v2f bIF = {(b_ih[ri] + b_hh[ri]) * si, (b_ih[rf] + b_hh[rf]) * si};
    const v2f bGO = {(b_ih[rg] + b_hh[rg]) * sg, (b_ih[ro] + b_hh[ro]) * si};

    // recurrent weights: scaled fp32 -> packed f16 pairs
    h2 wI[16], wF[16], wG[16], wO[16];
    #pragma unroll
    for (int k = 0; k < 16; ++k) {
        v2f a;
        a = ((const v2f*)(W_hh + ri * HH))[k] * si;
        wI[k] = (h2){(_Float16)a.x, (_Float16)a.y};
        a = ((const v2f*)(W_hh + rf * HH))[k] * si;
        wF[k] = (h2){(_Float16)a.x, (_Float16)a.y};
        a = ((const v2f*)(W_hh + rg * HH))[k] * sg;
        wG[k] = (h2){(_Float16)a.x, (_Float16)a.y};
        a = ((const v2f*)(W_hh + ro * HH))[k] * si;
        wO[k] = (h2){(_Float16)a.x, (_Float16)a.y};
    }

    // FC weights packed f16
    h2 wfc2[16];
    #pragma unroll
    for (int k = 0; k < 16; ++k) {
        v2f a = ((const v2f*)W_fc)[k];
        wfc2[k] = (h2){(_Float16)a.x, (_Float16)a.y};
    }
    const float bfc = b_fc[0];

    float c = 0.0f;   // c' = 2*log2e * c_true

    _Float16* hb = &lds_h[wv][low ? 0 : CHUNK * ROWH];
    _Float16* wr = hb + j;                        // row 0, col j

    hb[(CHUNK - 1) * ROWH + j] = (_Float16)0.0f;  // h_{-1} row = 0

    // h broadcast registers: 32 f16 = 4 x b128 (uniform addr per half-wave)
    v4u hq[4];
    {
        const v4u* rq = (const v4u*)(hb + (CHUNK - 1) * ROWH);
        #pragma unroll
        for (int q = 0; q < 4; ++q) hq[q] = rq[q];
    }

    const float* xb = x + (size_t)b * (TT * 2);
    float* outp = out + (size_t)b * TT + j;

    // x prefetch: 8 timesteps = 4 x b128 (4 unique addrs/wave)
    v4f xq0 = *(const v4f*)(xb);
    v4f xq1 = *(const v4f*)(xb + 4);
    v4f xq2 = *(const v4f*)(xb + 8);
    v4f xq3 = *(const v4f*)(xb + 12);

    #pragma unroll 1
    for (int ch = 0; ch < TT / CHUNK; ++ch) {
        #pragma unroll 1
        for (int uu = 0; uu < CHUNK; uu += 8) {
            const int t = ch * CHUNK + uu;
            const float* xnx = (t + 8 < TT) ? (xb + (t + 8) * 2) : xb;
            v4f nxq0 = *(const v4f*)(xnx);
            v4f nxq1 = *(const v4f*)(xnx + 4);
            v4f nxq2 = *(const v4f*)(xnx + 8);
            v4f nxq3 = *(const v4f*)(xnx + 12);

            #pragma unroll
            for (int s = 0; s < 8; ++s) {
                v2f xt;
                if      (s == 0) xt = (v2f){xq0.x, xq0.y};
                else if (s == 1) xt = (v2f){xq0.z, xq0.w};
                else if (s == 2) xt = (v2f){xq1.x, xq1.y};
                else if (s == 3) xt = (v2f){xq1.z, xq1.w};
                else if (s == 4) xt = (v2f){xq2.x, xq2.y};
                else if (s == 5) xt = (v2f){xq2.z, xq2.w};
                else if (s == 6) xt = (v2f){xq3.x, xq3.y};
                else             xt = (v2f){xq3.z, xq3.w};

                // x-projection + bias: 4 packed fma (gate pairs IF / GO);
                // per-half IEEE fma -> bit-identical to scalar version
                v2f sIF = __builtin_elementwise_fma(
                    (v2f){xt.x, xt.x}, wIFx, bIF);
                sIF = __builtin_elementwise_fma((v2f){xt.y, xt.y}, wIFy, sIF);
                v2f sGO = __builtin_elementwise_fma(
                    (v2f){xt.x, xt.x}, wGOx, bGO);
                sGO = __builtin_elementwise_fma((v2f){xt.y, xt.y}, wGOy, sGO);
                float aI0 = sIF.x, aF0 = sIF.y;
                float aG0 = sGO.x, aO0 = sGO.y;
                float aI1, aF1, aG1, aO1;

                // recurrent dot: 4 gates x 16 fdot2 (f16 MACs, fp32 accum),
                // split into 2 chains of 8 per gate
                #pragma unroll
                for (int k = 0; k < 16; ++k) {
                    h2 hp = u2h(hq[k >> 2][k & 3]);
                    if (k < 8) {
                        aI0 = FDOT2(hp, wI[k], aI0);
                        aF0 = FDOT2(hp, wF[k], aF0);
                        aG0 = FDOT2(hp, wG[k], aG0);
                        aO0 = FDOT2(hp, wO[k], aO0);
                    } else if (k == 8) {
                        aI1 = FDOT2(hp, wI[k], 0.0f);
                        aF1 = FDOT2(hp, wF[k], 0.0f);
                        aG1 = FDOT2(hp, wG[k], 0.0f);
                        aO1 = FDOT2(hp, wO[k], 0.0f);
                    } else {
                        aI1 = FDOT2(hp, wI[k], aI1);
                        aF1 = FDOT2(hp, wF[k], aF1);
                        aG1 = FDOT2(hp, wG[k], aG1);
                        aO1 = FDOT2(hp, wO[k], aO1);
                    }
                }
                // chain merges as packed adds (2x v_pk_add_f32)
                v2f gIF = (v2f){aI0, aF0} + (v2f){aI1, aF1};
                v2f gGO = (v2f){aG0, aO0} + (v2f){aG1, aO1};
                float gi = gIF.x, gf = gIF.y;
                float gg = gGO.x, go = gGO.y;

                // activations: all lane-local (fp32)
                float iv = sigm2(gi);
                float fv = sigm2(gf);
                float ov = sigm2(go);
                float gv = fmaf(4.0f * LOG2E, sigm2(gg), -2.0f * LOG2E);

                // c' = f*c' + i*g'   (2*log2e scale)
                c = fmaf(fv, c, iv * gv);

                // h = o*tanh(c) = fma(2*o, sigm(c'), -o)
                float rr   = sigm2(c);
                float hnew = fmaf(ov + ov, rr, -ov);

                // write h_t (f16); that row IS next step's broadcast source
                *wr = (_Float16)hnew;
                {
                    const v4u* rq = (const v4u*)(wr - j);
                    #pragma unroll
                    for (int q = 0; q < 4; ++q) hq[q] = rq[q];
                }
                wr += ROWH;
            }
            xq0 = nxq0; xq1 = nxq1; xq2 = nxq2; xq3 = nxq3;
        }

        // rewind write ptr; hq carries h across the chunk boundary
        wr -= CHUNK * ROWH;

        // ---- FC flush: lane j handles timestep t'=j of its element ----
        {
            const v4u* fr = (const v4u*)(hb + j * ROWH);
            v4u f[4];
            #pragma unroll
            for (int q = 0; q < 4; ++q) f[q] = fr[q];
            float acc = bfc;
            #pragma unroll
            for (int k = 0; k < 16; ++k)
                acc = FDOT2(u2h(f[k >> 2][k & 3]), wfc2[k], acc);
            *outp = acc;           // out[b][ch*CHUNK + j]
            outp += CHUNK;
        }
    }
}

extern "C" void kernel_launch(void* const* d_in, const int* in_sizes, int n_in,
                              void* d_out, int out_size, void* d_ws, size_t ws_size,
                              hipStream_t stream) {
    const float* x    = (const float*)d_in[0];
    const float* W_ih = (const float*)d_in[1];
    const float* W_hh = (const float*)d_in[2];
    const float* b_ih = (const float*)d_in[3];
    const float* b_hh = (const float*)d_in[4];
    const float* W_fc = (const float*)d_in[5];
    const float* b_fc = (const float*)d_in[6];
    float* out = (float*)d_out;

    dim3 grid(BB / 8);    // 256 blocks x 4 waves x 2 elements = 2048
    dim3 block(256);
    lstm_fused_kernel<<<grid, block, 0, stream>>>(x, W_ih, W_hh, b_ih, b_hh,
                                                  W_fc, b_fc, out);
}